// Round 6
// baseline (606.100 us; speedup 1.0000x reference)
//
#include <hip/hip_runtime.h>

#define S_DIM 512
#define H_DIM 512
#define NH 256
#define TI 8
#define TJ 8
#define NBLK 768   // 3 blocks/CU x 256 CUs: co-resident by construction (regs<=170/wave via
                   // launch_bounds(256,3); LDS 3x33.8KB <= 160KB) -> grid barrier is safe

#define AS1 __attribute__((address_space(1)))
#define AS3 __attribute__((address_space(3)))

typedef _Float16 half8 __attribute__((ext_vector_type(8)));
typedef _Float16 half4 __attribute__((ext_vector_type(4)));
typedef float f32x4 __attribute__((ext_vector_type(4)));

__device__ __forceinline__ int swz(int r) { return ((r & 1) << 2) | (r >> 1); }  // perm of 0..7

// device-scope grid barrier, replay-safe without counter reset requirements beyond
// per-launch memset: window-target scheme (target = ceil(my_arrival/NBLK)*NBLK).
__device__ __forceinline__ void grid_barrier(unsigned* cnt) {
    __syncthreads();
    if (threadIdx.x == 0) {
        __threadfence();                                   // release prior writes (agent scope)
        unsigned my = atomicAdd(cnt, 1u) + 1;              // device-scope atomic
        unsigned target = ((my + NBLK - 1) / NBLK) * NBLK;
        while (__hip_atomic_load(cnt, __ATOMIC_RELAXED, __HIP_MEMORY_SCOPE_AGENT) < target)
            __builtin_amdgcn_s_sleep(2);
        __threadfence();                                   // acquire: invalidate stale L1/L2
    }
    __syncthreads();
}

// ---------------- single persistent kernel: convert -> prep -> pair ----------------
__global__ __launch_bounds__(256, 3) void fused_kernel(
        const float* __restrict__ feats, const float* __restrict__ W1,
        const float* __restrict__ b1, const float* __restrict__ W2,
        const float* __restrict__ b2, const float* __restrict__ W3,
        const float* __restrict__ b3,
        _Float16* __restrict__ f16, _Float16* __restrict__ w1L, _Float16* __restrict__ w2L,
        _Float16* __restrict__ aH, _Float16* __restrict__ cH,
        float* __restrict__ out, unsigned* __restrict__ cnt) {

    __shared__ __align__(16) _Float16 sa[TI * H_DIM];     // 8 KB
    __shared__ __align__(16) _Float16 sc[TJ * H_DIM];     // 8 KB
    __shared__ __align__(16) _Float16 afb[2][2][4][512];  // 16 KB (2 bufs x 2 substeps x 4 frags)
    __shared__ float spart[4][64];                        // 1 KB

    const int tid = threadIdx.x;

    // ================= phase A: converts (832 block-units, grid-strided) =================
    for (int u = blockIdx.x; u < 832; u += NBLK) {
        if (u < 512) {
            int t = u * 256 + tid;                         // feats fp32 -> f16
            float4 v = ((const float4*)feats)[t];
            half4 h;
            h.x = (_Float16)v.x; h.y = (_Float16)v.y; h.z = (_Float16)v.z; h.w = (_Float16)v.w;
            ((half4*)f16)[t] = h;
        } else if (u < 768) {
            int t = (u - 512) * 256 + tid;                 // W1 -> fragment-major f16
            int gcb = t >> 10, n = t & 1023;
            const float* src = (n < H_DIM) ? &W1[(size_t)(gcb * 8) * H_DIM + n]
                                           : &W1[(size_t)(H_DIM + gcb * 8) * H_DIM + (n - H_DIM)];
            half8 v;
#pragma unroll
            for (int j = 0; j < 8; j++) v[j] = (_Float16)src[(size_t)j * H_DIM];
            *(half8*)&w1L[((size_t)gcb * 1024 + n) * 8] = v;
        } else {
            int t = (u - 768) * 256 + tid;                 // W2 -> fragment-major f16
            int gcb = t >> 8, n = t & 255;
            half8 v;
#pragma unroll
            for (int j = 0; j < 8; j++) v[j] = (_Float16)W2[(size_t)(gcb * 8 + j) * NH + n];
            *(half8*)&w2L[((size_t)gcb * 256 + n) * 8] = v;
        }
    }

    grid_barrier(cnt);

    // ================= phase B: prep GEMM [1024x512]@[512x1024] (256 units) =================
    for (int u = blockIdx.x; u < 256; u += NBLK) {
        const int n0 = (u & 15) * 64, m0 = (u >> 4) * 64;
        const int wave = tid >> 6, lane = tid & 63;
        const int quad = lane >> 4, l16 = lane & 15;
        const int wm = wave >> 1, wn = wave & 1;
        int mrow[2], ncol[2];
#pragma unroll
        for (int mt = 0; mt < 2; mt++) mrow[mt] = m0 + wm * 32 + mt * 16 + l16;
#pragma unroll
        for (int nt = 0; nt < 2; nt++) ncol[nt] = n0 + wn * 32 + nt * 16 + l16;
        f32x4 acc[2][2];
#pragma unroll
        for (int mt = 0; mt < 2; mt++)
#pragma unroll
            for (int nt = 0; nt < 2; nt++) acc[mt][nt] = (f32x4)0.f;
#pragma unroll
        for (int ks = 0; ks < 16; ks++) {
            int gcb = ks * 4 + quad;
            half8 af[2], bf[2];
#pragma unroll
            for (int mt = 0; mt < 2; mt++)
                af[mt] = *(const half8*)&f16[(size_t)mrow[mt] * H_DIM + gcb * 8];
#pragma unroll
            for (int nt = 0; nt < 2; nt++)
                bf[nt] = *(const half8*)&w1L[((size_t)gcb * 1024 + ncol[nt]) * 8];
#pragma unroll
            for (int nt = 0; nt < 2; nt++)
#pragma unroll
                for (int mt = 0; mt < 2; mt++)
                    acc[mt][nt] = __builtin_amdgcn_mfma_f32_16x16x32_f16(af[mt], bf[nt],
                                                                         acc[mt][nt], 0, 0, 0);
        }
        const bool first_half = (n0 < H_DIM);
#pragma unroll
        for (int nt = 0; nt < 2; nt++) {
            float bias = first_half ? b1[ncol[nt]] : 0.f;
#pragma unroll
            for (int mt = 0; mt < 2; mt++)
#pragma unroll
                for (int r = 0; r < 4; r++) {
                    int m = m0 + wm * 32 + mt * 16 + quad * 4 + r;
                    float v = acc[mt][nt][r] + bias;
                    if (first_half) aH[(size_t)m * H_DIM + ncol[nt]] = (_Float16)v;
                    else            cH[(size_t)m * H_DIM + (ncol[nt] - H_DIM)] = (_Float16)v;
                }
        }
    }

    grid_barrier(cnt);

    // ================= phase C: pair GEMM (8192 tiles, 10-11 per block) =================
    // body identical to the proven 128.4us pair_kernel (R5): LDS-shared af fragments,
    // K64 barrier epochs, raw s_barrier (B-prefetch stays in flight), T5 setprio.
    const int wave = tid >> 6, lane = tid & 63;
    const int quad = lane >> 4, l16 = lane & 15;
    const int nb = wave * 64;
    const int hl = l16 >> 3;
    const int ilW = wave * 2 + hl;
    const int saoffW = ilW * H_DIM;
    const int swzAW = swz(ilW);
    const int jl = l16 & 7;
    const int scoff = jl * H_DIM, swzC = swz(jl);

    for (int t = blockIdx.x; t < 64 * 64 * 2; t += NBLK) {
        const int jt = t & 63, it = (t >> 6) & 63, b = t >> 12;
        const int i0 = it * TI, j0 = jt * TJ;

        // ---- stage a rows (8) and c rows (8), swizzled ----
#pragma unroll
        for (int rr0 = 0; rr0 < 2; rr0++) {
            int rr = rr0 * 4 + wave;
            int gc = lane ^ swz(rr & 7);
            __builtin_amdgcn_global_load_lds(
                (const AS1 unsigned int*)&aH[((size_t)(b * S_DIM + i0 + rr)) * H_DIM + gc * 8],
                (AS3 unsigned int*)&sa[rr * H_DIM], 16, 0, 0);
            __builtin_amdgcn_global_load_lds(
                (const AS1 unsigned int*)&cH[((size_t)(b * S_DIM + j0 + rr)) * H_DIM + gc * 8],
                (AS3 unsigned int*)&sc[rr * H_DIM], 16, 0, 0);
        }

        f32x4 acc[4][4];
#pragma unroll
        for (int mt = 0; mt < 4; mt++)
#pragma unroll
            for (int nt = 0; nt < 4; nt++) acc[mt][nt] = (f32x4)0.f;

        const _Float16* bp = &w2L[((size_t)quad * 256 + nb + l16) * 8];
        half8 bnxt[4];
#pragma unroll
        for (int nt = 0; nt < 4; nt++) bnxt[nt] = *(const half8*)&bp[nt * 16 * 8];

        __syncthreads();   // sa/sc staged (drains DMA)

        // prologue: this wave's frags for epoch 0 (ks = 0,1) into buffer 0
#pragma unroll
        for (int s = 0; s < 2; s++) {
            const int gcb = s * 4 + quad;
            half8 va = *(const half8*)&sa[saoffW + ((gcb ^ swzAW) * 8)];
            half8 vc = *(const half8*)&sc[scoff + ((gcb ^ swzC) * 8)];
            half8 af = __builtin_elementwise_max(va + vc, (half8)(_Float16)0.f);
            *(half8*)&afb[0][s][wave][lane * 8] = af;
        }
        asm volatile("s_waitcnt lgkmcnt(0)" ::: "memory");
        __builtin_amdgcn_s_barrier();
        __builtin_amdgcn_sched_barrier(0);

#pragma unroll
        for (int e = 0; e < 8; e++) {
            const int buf = e & 1;
#pragma unroll
            for (int s = 0; s < 2; s++) {
                const int ks = e * 2 + s;
                half8 bf[4];
#pragma unroll
                for (int nt = 0; nt < 4; nt++) bf[nt] = bnxt[nt];
                if (ks < 15) {
                    const _Float16* bn = bp + (size_t)4 * 256 * 8;
#pragma unroll
                    for (int nt = 0; nt < 4; nt++) bnxt[nt] = *(const half8*)&bn[nt * 16 * 8];
                    bp = bn;
                }
                if (e < 7) {
                    const int gcb = (2 * (e + 1) + s) * 4 + quad;
                    half8 va = *(const half8*)&sa[saoffW + ((gcb ^ swzAW) * 8)];
                    half8 vc = *(const half8*)&sc[scoff + ((gcb ^ swzC) * 8)];
                    half8 af = __builtin_elementwise_max(va + vc, (half8)(_Float16)0.f);
                    *(half8*)&afb[buf ^ 1][s][wave][lane * 8] = af;
                }
                half8 afr[4];
#pragma unroll
                for (int mt = 0; mt < 4; mt++)
                    afr[mt] = *(const half8*)&afb[buf][s][mt][lane * 8];
                __builtin_amdgcn_s_setprio(1);
#pragma unroll
                for (int nt = 0; nt < 4; nt++)
#pragma unroll
                    for (int mt = 0; mt < 4; mt++)
                        acc[mt][nt] = __builtin_amdgcn_mfma_f32_16x16x32_f16(afr[mt], bf[nt],
                                                                             acc[mt][nt], 0, 0, 0);
                __builtin_amdgcn_s_setprio(0);
            }
            if (e < 7) {
                asm volatile("s_waitcnt lgkmcnt(0)" ::: "memory");
                __builtin_amdgcn_s_barrier();
                __builtin_amdgcn_sched_barrier(0);
            }
        }

        // ---- fused epilogue: h2 = relu(acc+b2); partial logit = h2 . W3 ----
        float b2v[4], w3v[4];
#pragma unroll
        for (int nt = 0; nt < 4; nt++) {
            int n = nb + nt * 16 + l16;
            b2v[nt] = b2[n];
            w3v[nt] = W3[n];
        }
        float ps[4][4];
#pragma unroll
        for (int mt = 0; mt < 4; mt++)
#pragma unroll
            for (int r = 0; r < 4; r++) {
                float s = 0.f;
#pragma unroll
                for (int nt = 0; nt < 4; nt++) {
                    float v = acc[mt][nt][r] + b2v[nt];
                    v = v > 0.f ? v : 0.f;
                    s += v * w3v[nt];
                }
                ps[mt][r] = s;
            }
#pragma unroll
        for (int mt = 0; mt < 4; mt++)
#pragma unroll
            for (int r = 0; r < 4; r++) {
                float s = ps[mt][r];
                s += __shfl_xor(s, 8, 16);
                s += __shfl_xor(s, 4, 16);
                s += __shfl_xor(s, 2, 16);
                s += __shfl_xor(s, 1, 16);
                ps[mt][r] = s;
            }
        if (l16 == 0) {
#pragma unroll
            for (int mt = 0; mt < 4; mt++)
#pragma unroll
                for (int r = 0; r < 4; r++)
                    spart[wave][mt * 16 + quad * 4 + r] = ps[mt][r];
        }
        __syncthreads();
        if (tid < 64) {
            float tot = spart[0][tid] + spart[1][tid] + spart[2][tid] + spart[3][tid] + b3[0];
            float sg = 1.f / (1.f + __expf(-tot));
            int i = i0 + (tid >> 3), j = j0 + (tid & 7);
            out[(size_t)b * S_DIM * S_DIM + (size_t)i * S_DIM + j] = sg;
        }
        __syncthreads();   // spart/out consumed before next tile reuses LDS
    }
}

extern "C" void kernel_launch(void* const* d_in, const int* in_sizes, int n_in,
                              void* d_out, int out_size, void* d_ws, size_t ws_size,
                              hipStream_t stream) {
    const float* feats = (const float*)d_in[0];
    const float* W1 = (const float*)d_in[1];
    const float* b1 = (const float*)d_in[2];
    const float* W2 = (const float*)d_in[3];
    const float* b2 = (const float*)d_in[4];
    const float* W3 = (const float*)d_in[5];
    const float* b3 = (const float*)d_in[6];
    float* out = (float*)d_out;

    char* ws = (char*)d_ws;
    _Float16* f16  = (_Float16*)ws;                 // [1024][512] = 1 MB
    _Float16* aH   = (_Float16*)(ws + (1 << 20));   // [1024][512] = 1 MB
    _Float16* cH   = (_Float16*)(ws + (2 << 20));   // [1024][512] = 1 MB
    _Float16* w1L  = (_Float16*)(ws + (3 << 20));   // 1 MB
    _Float16* w2L  = (_Float16*)(ws + (4 << 20));   // 256 KB
    unsigned* cnt  = (unsigned*)(ws + (4 << 20) + (256 << 10));  // grid-barrier counter

    hipMemsetAsync(cnt, 0, 16, stream);             // replay-safe barrier windows
    fused_kernel<<<NBLK, 256, 0, stream>>>(feats, W1, b1, W2, b2, W3, b3,
                                           f16, w1L, w2L, aH, cH, out, cnt);
}

// Round 7
// 203.921 us; speedup vs baseline: 2.9722x; 2.9722x over previous
//
#include <hip/hip_runtime.h>

#define S_DIM 512
#define H_DIM 512
#define NH 256
#define TI 8
#define TJ 8

#define AS1 __attribute__((address_space(1)))
#define AS3 __attribute__((address_space(3)))

typedef _Float16 half8 __attribute__((ext_vector_type(8)));
typedef float f32x4 __attribute__((ext_vector_type(4)));

__device__ __forceinline__ int swz(int r) { return ((r & 1) << 2) | (r >> 1); }  // perm of 0..7

// ---------------- k1': fused prep GEMM + W2 layout-convert (replaces k0+k1) ----------------
// grid = 16*mblocks + 64 blocks of 256.
//  blocks [0, 16*mblocks): prep GEMM. Block = 32 m-rows x 64 n-cols. feats converted
//    fp32->f16 IN-REGISTER (same cast point as old k0 -> bit-identical); W1 panel staged
//    per K32-chunk through an LDS transpose tile (coalesced fp32 row reads -> f16 [n][h],
//    80B padded stride -> 2-way max on ds_read_b128 fragments).
//  blocks [16*mblocks, +64): W2 -> fragment-major w2L (identical to old k0 section;
//    w2L is consumed only by pair_kernel -> no cross-block dependency).
__global__ __launch_bounds__(256) void prep_fused_kernel(
        const float* __restrict__ feats, const float* __restrict__ W1,
        const float* __restrict__ b1, const float* __restrict__ W2,
        _Float16* __restrict__ aH, _Float16* __restrict__ cH,
        _Float16* __restrict__ w2L, int mblocks) {
    const int tid = threadIdx.x;
    const int blk = blockIdx.x;

    if (blk >= 16 * mblocks) {                       // ---- W2 -> w2L (64 blocks) ----
        int t = (blk - 16 * mblocks) * 256 + tid;    // 16384 threads
        int gcb = t >> 8, n = t & 255;
        half8 v;
#pragma unroll
        for (int j = 0; j < 8; j++) v[j] = (_Float16)W2[(size_t)(gcb * 8 + j) * NH + n];
        *(half8*)&w2L[((size_t)gcb * 256 + n) * 8] = v;
        return;
    }

    // ---- prep GEMM block ----
    __shared__ __align__(16) _Float16 sw1T[64][40];  // [n_local][h_local], 80B row stride

    const int n0 = (blk & 15) * 64, m0 = (blk >> 4) * 32;
    const int wave = tid >> 6, lane = tid & 63;
    const int quad = lane >> 4, l16 = lane & 15;
    const int wm = wave >> 1, wn = wave & 1;

    const int mrow = m0 + wm * 16 + l16;
    int ncol[2];
#pragma unroll
    for (int nt = 0; nt < 2; nt++) ncol[nt] = n0 + wn * 32 + nt * 16 + l16;

    const bool first_half = (n0 < H_DIM);
    const int rbase = first_half ? 0 : H_DIM;
    const int cbase = first_half ? n0 : (n0 - H_DIM);

    const int n4 = tid & 15, hh = tid >> 4;          // staging roles: 16x4 cols, 16 h-rows

    f32x4 acc[2];
#pragma unroll
    for (int nt = 0; nt < 2; nt++) acc[nt] = (f32x4)0.f;

    for (int ks = 0; ks < 16; ks++) {
        __syncthreads();                             // WAR: prior fragment reads done
        // stage W1[rbase+ks*32 .. +32][cbase .. +64] fp32 -> sw1T[n][h] f16 (transposed)
        const float* wsrc = &W1[(size_t)(rbase + ks * 32) * H_DIM + cbase];
#pragma unroll
        for (int p = 0; p < 2; p++) {
            float4 v = *(const float4*)&wsrc[(size_t)(hh + p * 16) * H_DIM + n4 * 4];
            sw1T[n4 * 4 + 0][hh + p * 16] = (_Float16)v.x;
            sw1T[n4 * 4 + 1][hh + p * 16] = (_Float16)v.y;
            sw1T[n4 * 4 + 2][hh + p * 16] = (_Float16)v.z;
            sw1T[n4 * 4 + 3][hh + p * 16] = (_Float16)v.w;
        }
        __syncthreads();
        // af: feats fp32 -> f16 in-register (h = ks*32 + quad*8 + j, same as old gcb*8+j)
        const float* fp = &feats[(size_t)mrow * H_DIM + ks * 32 + quad * 8];
        float4 a0 = ((const float4*)fp)[0], a1 = ((const float4*)fp)[1];
        half8 af;
        af[0] = (_Float16)a0.x; af[1] = (_Float16)a0.y;
        af[2] = (_Float16)a0.z; af[3] = (_Float16)a0.w;
        af[4] = (_Float16)a1.x; af[5] = (_Float16)a1.y;
        af[6] = (_Float16)a1.z; af[7] = (_Float16)a1.w;
        half8 bf[2];
#pragma unroll
        for (int nt = 0; nt < 2; nt++)
            bf[nt] = *(const half8*)&sw1T[wn * 32 + nt * 16 + l16][quad * 8];
#pragma unroll
        for (int nt = 0; nt < 2; nt++)
            acc[nt] = __builtin_amdgcn_mfma_f32_16x16x32_f16(af, bf[nt], acc[nt], 0, 0, 0);
    }

#pragma unroll
    for (int nt = 0; nt < 2; nt++) {
        float bias = first_half ? b1[ncol[nt]] : 0.f;
#pragma unroll
        for (int r = 0; r < 4; r++) {
            int m = m0 + wm * 16 + quad * 4 + r;
            float v = acc[nt][r] + bias;
            if (first_half) aH[(size_t)m * H_DIM + ncol[nt]] = (_Float16)v;
            else            cH[(size_t)m * H_DIM + (ncol[nt] - H_DIM)] = (_Float16)v;
        }
    }
}

// ---------------- k2: pair GEMM, LDS-shared af fragments, K64 barrier epochs ----------------
// BYTE-IDENTICAL to the proven 128.4us R5 kernel (frozen for clean attribution).
__global__ __launch_bounds__(256, 4) void pair_kernel(
        const _Float16* __restrict__ aH, const _Float16* __restrict__ cH,
        const _Float16* __restrict__ w2L,
        const float* __restrict__ b2, const float* __restrict__ W3,
        const float* __restrict__ b3, float* __restrict__ out) {
    const int jt = blockIdx.x, it = blockIdx.y, b = blockIdx.z;
    const int i0 = it * TI, j0 = jt * TJ;

    __shared__ __align__(16) _Float16 sa[TI * H_DIM];     // 8 KB
    __shared__ __align__(16) _Float16 sc[TJ * H_DIM];     // 8 KB
    __shared__ __align__(16) _Float16 afb[2][2][4][512];  // 16 KB (2 bufs x 2 substeps x 4 frags)
    __shared__ float spart[4][64];                        // 1 KB

    const int tid = threadIdx.x;
    const int wave = tid >> 6, lane = tid & 63;
    const int quad = lane >> 4, l16 = lane & 15;
    const int nb = wave * 64;

#pragma unroll
    for (int rr0 = 0; rr0 < 2; rr0++) {
        int rr = rr0 * 4 + wave;
        int gc = lane ^ swz(rr & 7);
        __builtin_amdgcn_global_load_lds(
            (const AS1 unsigned int*)&aH[((size_t)(b * S_DIM + i0 + rr)) * H_DIM + gc * 8],
            (AS3 unsigned int*)&sa[rr * H_DIM], 16, 0, 0);
        __builtin_amdgcn_global_load_lds(
            (const AS1 unsigned int*)&cH[((size_t)(b * S_DIM + j0 + rr)) * H_DIM + gc * 8],
            (AS3 unsigned int*)&sc[rr * H_DIM], 16, 0, 0);
    }

    const int hl = l16 >> 3;
    const int ilW = wave * 2 + hl;
    const int saoffW = ilW * H_DIM;
    const int swzAW = swz(ilW);
    const int jl = l16 & 7;
    const int scoff = jl * H_DIM, swzC = swz(jl);

    f32x4 acc[4][4];
#pragma unroll
    for (int mt = 0; mt < 4; mt++)
#pragma unroll
        for (int nt = 0; nt < 4; nt++) acc[mt][nt] = (f32x4)0.f;

    const _Float16* bp = &w2L[((size_t)quad * 256 + nb + l16) * 8];

    half8 bnxt[4];
#pragma unroll
    for (int nt = 0; nt < 4; nt++) bnxt[nt] = *(const half8*)&bp[nt * 16 * 8];

    __syncthreads();   // sa/sc staged (drains DMA)

#pragma unroll
    for (int s = 0; s < 2; s++) {
        const int gcb = s * 4 + quad;
        half8 va = *(const half8*)&sa[saoffW + ((gcb ^ swzAW) * 8)];
        half8 vc = *(const half8*)&sc[scoff + ((gcb ^ swzC) * 8)];
        half8 af = __builtin_elementwise_max(va + vc, (half8)(_Float16)0.f);
        *(half8*)&afb[0][s][wave][lane * 8] = af;
    }
    asm volatile("s_waitcnt lgkmcnt(0)" ::: "memory");
    __builtin_amdgcn_s_barrier();
    __builtin_amdgcn_sched_barrier(0);

#pragma unroll
    for (int e = 0; e < 8; e++) {
        const int buf = e & 1;
#pragma unroll
        for (int s = 0; s < 2; s++) {
            const int ks = e * 2 + s;
            half8 bf[4];
#pragma unroll
            for (int nt = 0; nt < 4; nt++) bf[nt] = bnxt[nt];
            if (ks < 15) {
                const _Float16* bn = bp + (size_t)4 * 256 * 8;
#pragma unroll
                for (int nt = 0; nt < 4; nt++) bnxt[nt] = *(const half8*)&bn[nt * 16 * 8];
                bp = bn;
            }
            if (e < 7) {
                const int gcb = (2 * (e + 1) + s) * 4 + quad;
                half8 va = *(const half8*)&sa[saoffW + ((gcb ^ swzAW) * 8)];
                half8 vc = *(const half8*)&sc[scoff + ((gcb ^ swzC) * 8)];
                half8 af = __builtin_elementwise_max(va + vc, (half8)(_Float16)0.f);
                *(half8*)&afb[buf ^ 1][s][wave][lane * 8] = af;
            }
            half8 afr[4];
#pragma unroll
            for (int mt = 0; mt < 4; mt++)
                afr[mt] = *(const half8*)&afb[buf][s][mt][lane * 8];
            __builtin_amdgcn_s_setprio(1);
#pragma unroll
            for (int nt = 0; nt < 4; nt++)
#pragma unroll
                for (int mt = 0; mt < 4; mt++)
                    acc[mt][nt] = __builtin_amdgcn_mfma_f32_16x16x32_f16(afr[mt], bf[nt],
                                                                         acc[mt][nt], 0, 0, 0);
            __builtin_amdgcn_s_setprio(0);
        }
        if (e < 7) {
            asm volatile("s_waitcnt lgkmcnt(0)" ::: "memory");
            __builtin_amdgcn_s_barrier();
            __builtin_amdgcn_sched_barrier(0);
        }
    }

    float b2v[4], w3v[4];
#pragma unroll
    for (int nt = 0; nt < 4; nt++) {
        int n = nb + nt * 16 + l16;
        b2v[nt] = b2[n];
        w3v[nt] = W3[n];
    }
    float ps[4][4];
#pragma unroll
    for (int mt = 0; mt < 4; mt++)
#pragma unroll
        for (int r = 0; r < 4; r++) {
            float s = 0.f;
#pragma unroll
            for (int nt = 0; nt < 4; nt++) {
                float v = acc[mt][nt][r] + b2v[nt];
                v = v > 0.f ? v : 0.f;
                s += v * w3v[nt];
            }
            ps[mt][r] = s;
        }
#pragma unroll
    for (int mt = 0; mt < 4; mt++)
#pragma unroll
        for (int r = 0; r < 4; r++) {
            float s = ps[mt][r];
            s += __shfl_xor(s, 8, 16);
            s += __shfl_xor(s, 4, 16);
            s += __shfl_xor(s, 2, 16);
            s += __shfl_xor(s, 1, 16);
            ps[mt][r] = s;
        }
    if (l16 == 0) {
#pragma unroll
        for (int mt = 0; mt < 4; mt++)
#pragma unroll
            for (int r = 0; r < 4; r++)
                spart[wave][mt * 16 + quad * 4 + r] = ps[mt][r];
    }
    __syncthreads();
    if (tid < 64) {
        float tot = spart[0][tid] + spart[1][tid] + spart[2][tid] + spart[3][tid] + b3[0];
        float sg = 1.f / (1.f + __expf(-tot));
        int i = i0 + (tid >> 3), j = j0 + (tid & 7);
        out[(size_t)b * S_DIM * S_DIM + (size_t)i * S_DIM + j] = sg;
    }
}

extern "C" void kernel_launch(void* const* d_in, const int* in_sizes, int n_in,
                              void* d_out, int out_size, void* d_ws, size_t ws_size,
                              hipStream_t stream) {
    const float* feats = (const float*)d_in[0];
    const float* W1 = (const float*)d_in[1];
    const float* b1 = (const float*)d_in[2];
    const float* W2 = (const float*)d_in[3];
    const float* b2 = (const float*)d_in[4];
    const float* W3 = (const float*)d_in[5];
    const float* b3 = (const float*)d_in[6];
    float* out = (float*)d_out;

    const int B = in_sizes[0] / (S_DIM * H_DIM);   // = 2
    const int M = B * S_DIM;                       // 1024
    const int mblocks = M / 32;                    // 32

    char* ws = (char*)d_ws;
    _Float16* aH   = (_Float16*)ws;                 // [1024][512] = 1 MB
    _Float16* cH   = (_Float16*)(ws + (1 << 20));   // [1024][512] = 1 MB
    _Float16* w2L  = (_Float16*)(ws + (2 << 20));   // 256 KB

    prep_fused_kernel<<<16 * mblocks + 64, 256, 0, stream>>>(feats, W1, b1, W2,
                                                             aH, cH, w2L, mblocks);
    pair_kernel<<<dim3(S_DIM / TJ, S_DIM / TI, B), 256, 0, stream>>>(aH, cH, w2L, b2, W3, b3, out);
}

// Round 8
// 201.802 us; speedup vs baseline: 3.0034x; 1.0105x over previous
//
#include <hip/hip_runtime.h>

#define S_DIM 512
#define H_DIM 512
#define NH 256
#define TI 8
#define TJ 8

#define AS1 __attribute__((address_space(1)))
#define AS3 __attribute__((address_space(3)))

typedef _Float16 half8 __attribute__((ext_vector_type(8)));
typedef _Float16 half4 __attribute__((ext_vector_type(4)));
typedef float f32x4 __attribute__((ext_vector_type(4)));

__device__ __forceinline__ int swz(int r) { return ((r & 1) << 2) | (r >> 1); }  // perm of 0..7

// ---------------- k0: fused converts ----------------
__global__ __launch_bounds__(256) void convert_all_kernel(const float* __restrict__ feats,
        const float* __restrict__ W1, const float* __restrict__ W2,
        _Float16* __restrict__ f16, _Float16* __restrict__ w1L, _Float16* __restrict__ w2L) {
    int blk = blockIdx.x;
    if (blk < 512) {
        int t = blk * 256 + threadIdx.x;           // 131072 threads, 4 elems each
        float4 v = ((const float4*)feats)[t];
        half4 h;
        h.x = (_Float16)v.x; h.y = (_Float16)v.y; h.z = (_Float16)v.z; h.w = (_Float16)v.w;
        ((half4*)f16)[t] = h;
    } else if (blk < 768) {
        int t = (blk - 512) * 256 + threadIdx.x;   // 65536
        int gcb = t >> 10, n = t & 1023;
        const float* src = (n < H_DIM) ? &W1[(size_t)(gcb * 8) * H_DIM + n]
                                       : &W1[(size_t)(H_DIM + gcb * 8) * H_DIM + (n - H_DIM)];
        half8 v;
#pragma unroll
        for (int j = 0; j < 8; j++) v[j] = (_Float16)src[(size_t)j * H_DIM];
        *(half8*)&w1L[((size_t)gcb * 1024 + n) * 8] = v;
    } else {
        int t = (blk - 768) * 256 + threadIdx.x;   // 16384
        int gcb = t >> 8, n = t & 255;
        half8 v;
#pragma unroll
        for (int j = 0; j < 8; j++) v[j] = (_Float16)W2[(size_t)(gcb * 8 + j) * NH + n];
        *(half8*)&w2L[((size_t)gcb * 256 + n) * 8] = v;
    }
}

// ---------------- k1: prep GEMM  [1024 x 512] @ [512 x 1024] f16 MFMA --------------
__global__ __launch_bounds__(256) void prep_mfma_kernel(const _Float16* __restrict__ f16,
        const _Float16* __restrict__ w1L, const float* __restrict__ b1,
        _Float16* __restrict__ aH, _Float16* __restrict__ cH) {
    const int n0 = blockIdx.x * 64, m0 = blockIdx.y * 64;
    const int tid = threadIdx.x, wave = tid >> 6, lane = tid & 63;
    const int quad = lane >> 4, l16 = lane & 15;
    const int wm = wave >> 1, wn = wave & 1;
    int mrow[2], ncol[2];
#pragma unroll
    for (int mt = 0; mt < 2; mt++) mrow[mt] = m0 + wm * 32 + mt * 16 + l16;
#pragma unroll
    for (int nt = 0; nt < 2; nt++) ncol[nt] = n0 + wn * 32 + nt * 16 + l16;
    f32x4 acc[2][2];
#pragma unroll
    for (int mt = 0; mt < 2; mt++)
#pragma unroll
        for (int nt = 0; nt < 2; nt++) acc[mt][nt] = (f32x4)0.f;
#pragma unroll
    for (int ks = 0; ks < 16; ks++) {
        int gcb = ks * 4 + quad;
        half8 af[2], bf[2];
#pragma unroll
        for (int mt = 0; mt < 2; mt++)
            af[mt] = *(const half8*)&f16[(size_t)mrow[mt] * H_DIM + gcb * 8];
#pragma unroll
        for (int nt = 0; nt < 2; nt++)
            bf[nt] = *(const half8*)&w1L[((size_t)gcb * 1024 + ncol[nt]) * 8];
#pragma unroll
        for (int nt = 0; nt < 2; nt++)
#pragma unroll
            for (int mt = 0; mt < 2; mt++)
                acc[mt][nt] = __builtin_amdgcn_mfma_f32_16x16x32_f16(af[mt], bf[nt],
                                                                     acc[mt][nt], 0, 0, 0);
    }
    const bool first_half = (n0 < H_DIM);
#pragma unroll
    for (int nt = 0; nt < 2; nt++) {
        float bias = first_half ? b1[ncol[nt]] : 0.f;
#pragma unroll
        for (int mt = 0; mt < 2; mt++)
#pragma unroll
            for (int r = 0; r < 4; r++) {
                int m = m0 + wm * 32 + mt * 16 + quad * 4 + r;
                float v = acc[mt][nt][r] + bias;
                if (first_half) aH[(size_t)m * H_DIM + ncol[nt]] = (_Float16)v;
                else            cH[(size_t)m * H_DIM + (ncol[nt] - H_DIM)] = (_Float16)v;
            }
    }
}

// ---------------- k2: pair GEMM (R5 body) + co-resident-block PHASE STAGGER ----------------
// Model (R7 post-mortem): wall = LDS-pipe demand (72us, 7 b128 ops/wave/K-step @ 12cyc) +
// MFMA demand (66us) nearly SERIALIZED, because the 4 co-resident blocks/CU start together
// and stay barrier-phase-aligned -> collective LDS phase idles the MFMA pipe and vice versa.
// Fix: one-time s_sleep stagger (quarter-epoch steps) for the first resident generation;
// later generations inherit the offset from predecessors' staggered finish times.
__global__ __launch_bounds__(256, 4) void pair_kernel(
        const _Float16* __restrict__ aH, const _Float16* __restrict__ cH,
        const _Float16* __restrict__ w2L,
        const float* __restrict__ b2, const float* __restrict__ W3,
        const float* __restrict__ b3, float* __restrict__ out) {
    const int jt = blockIdx.x, it = blockIdx.y, b = blockIdx.z;
    const int i0 = it * TI, j0 = jt * TJ;

    // ---- phase stagger: key works for both stride-256 round-robin and packed mappings ----
    {
        const int lin = b * 4096 + it * 64 + jt;
        if (lin < 1024) {
            const int slot = ((lin >> 8) ^ lin) & 3;
            for (int k = 0; k < slot; k++)
                __builtin_amdgcn_s_sleep(19);        // ~1216 cyc each ~= quarter epoch
        }
    }

    __shared__ __align__(16) _Float16 sa[TI * H_DIM];     // 8 KB
    __shared__ __align__(16) _Float16 sc[TJ * H_DIM];     // 8 KB
    __shared__ __align__(16) _Float16 afb[2][2][4][512];  // 16 KB
    __shared__ float spart[4][64];                        // 1 KB

    const int tid = threadIdx.x;
    const int wave = tid >> 6, lane = tid & 63;
    const int quad = lane >> 4, l16 = lane & 15;
    const int nb = wave * 64;

#pragma unroll
    for (int rr0 = 0; rr0 < 2; rr0++) {
        int rr = rr0 * 4 + wave;
        int gc = lane ^ swz(rr & 7);
        __builtin_amdgcn_global_load_lds(
            (const AS1 unsigned int*)&aH[((size_t)(b * S_DIM + i0 + rr)) * H_DIM + gc * 8],
            (AS3 unsigned int*)&sa[rr * H_DIM], 16, 0, 0);
        __builtin_amdgcn_global_load_lds(
            (const AS1 unsigned int*)&cH[((size_t)(b * S_DIM + j0 + rr)) * H_DIM + gc * 8],
            (AS3 unsigned int*)&sc[rr * H_DIM], 16, 0, 0);
    }

    const int hl = l16 >> 3;
    const int ilW = wave * 2 + hl;
    const int saoffW = ilW * H_DIM;
    const int swzAW = swz(ilW);
    const int jl = l16 & 7;
    const int scoff = jl * H_DIM, swzC = swz(jl);

    f32x4 acc[4][4];
#pragma unroll
    for (int mt = 0; mt < 4; mt++)
#pragma unroll
        for (int nt = 0; nt < 4; nt++) acc[mt][nt] = (f32x4)0.f;

    const _Float16* bp = &w2L[((size_t)quad * 256 + nb + l16) * 8];

    half8 bnxt[4];
#pragma unroll
    for (int nt = 0; nt < 4; nt++) bnxt[nt] = *(const half8*)&bp[nt * 16 * 8];

    __syncthreads();   // sa/sc staged (drains DMA)

#pragma unroll
    for (int s = 0; s < 2; s++) {
        const int gcb = s * 4 + quad;
        half8 va = *(const half8*)&sa[saoffW + ((gcb ^ swzAW) * 8)];
        half8 vc = *(const half8*)&sc[scoff + ((gcb ^ swzC) * 8)];
        half8 af = __builtin_elementwise_max(va + vc, (half8)(_Float16)0.f);
        *(half8*)&afb[0][s][wave][lane * 8] = af;
    }
    asm volatile("s_waitcnt lgkmcnt(0)" ::: "memory");
    __builtin_amdgcn_s_barrier();
    __builtin_amdgcn_sched_barrier(0);

#pragma unroll
    for (int e = 0; e < 8; e++) {
        const int buf = e & 1;
#pragma unroll
        for (int s = 0; s < 2; s++) {
            const int ks = e * 2 + s;
            half8 bf[4];
#pragma unroll
            for (int nt = 0; nt < 4; nt++) bf[nt] = bnxt[nt];
            if (ks < 15) {
                const _Float16* bn = bp + (size_t)4 * 256 * 8;
#pragma unroll
                for (int nt = 0; nt < 4; nt++) bnxt[nt] = *(const half8*)&bn[nt * 16 * 8];
                bp = bn;
            }
            if (e < 7) {
                const int gcb = (2 * (e + 1) + s) * 4 + quad;
                half8 va = *(const half8*)&sa[saoffW + ((gcb ^ swzAW) * 8)];
                half8 vc = *(const half8*)&sc[scoff + ((gcb ^ swzC) * 8)];
                half8 af = __builtin_elementwise_max(va + vc, (half8)(_Float16)0.f);
                *(half8*)&afb[buf ^ 1][s][wave][lane * 8] = af;
            }
            half8 afr[4];
#pragma unroll
            for (int mt = 0; mt < 4; mt++)
                afr[mt] = *(const half8*)&afb[buf][s][mt][lane * 8];
            __builtin_amdgcn_s_setprio(1);
#pragma unroll
            for (int nt = 0; nt < 4; nt++)
#pragma unroll
                for (int mt = 0; mt < 4; mt++)
                    acc[mt][nt] = __builtin_amdgcn_mfma_f32_16x16x32_f16(afr[mt], bf[nt],
                                                                         acc[mt][nt], 0, 0, 0);
            __builtin_amdgcn_s_setprio(0);
        }
        if (e < 7) {
            asm volatile("s_waitcnt lgkmcnt(0)" ::: "memory");
            __builtin_amdgcn_s_barrier();
            __builtin_amdgcn_sched_barrier(0);
        }
    }

    float b2v[4], w3v[4];
#pragma unroll
    for (int nt = 0; nt < 4; nt++) {
        int n = nb + nt * 16 + l16;
        b2v[nt] = b2[n];
        w3v[nt] = W3[n];
    }
    float ps[4][4];
#pragma unroll
    for (int mt = 0; mt < 4; mt++)
#pragma unroll
        for (int r = 0; r < 4; r++) {
            float s = 0.f;
#pragma unroll
            for (int nt = 0; nt < 4; nt++) {
                float v = acc[mt][nt][r] + b2v[nt];
                v = v > 0.f ? v : 0.f;
                s += v * w3v[nt];
            }
            ps[mt][r] = s;
        }
#pragma unroll
    for (int mt = 0; mt < 4; mt++)
#pragma unroll
        for (int r = 0; r < 4; r++) {
            float s = ps[mt][r];
            s += __shfl_xor(s, 8, 16);
            s += __shfl_xor(s, 4, 16);
            s += __shfl_xor(s, 2, 16);
            s += __shfl_xor(s, 1, 16);
            ps[mt][r] = s;
        }
    if (l16 == 0) {
#pragma unroll
        for (int mt = 0; mt < 4; mt++)
#pragma unroll
            for (int r = 0; r < 4; r++)
                spart[wave][mt * 16 + quad * 4 + r] = ps[mt][r];
    }
    __syncthreads();
    if (tid < 64) {
        float tot = spart[0][tid] + spart[1][tid] + spart[2][tid] + spart[3][tid] + b3[0];
        float sg = 1.f / (1.f + __expf(-tot));
        int i = i0 + (tid >> 3), j = j0 + (tid & 7);
        out[(size_t)b * S_DIM * S_DIM + (size_t)i * S_DIM + j] = sg;
    }
}

extern "C" void kernel_launch(void* const* d_in, const int* in_sizes, int n_in,
                              void* d_out, int out_size, void* d_ws, size_t ws_size,
                              hipStream_t stream) {
    const float* feats = (const float*)d_in[0];
    const float* W1 = (const float*)d_in[1];
    const float* b1 = (const float*)d_in[2];
    const float* W2 = (const float*)d_in[3];
    const float* b2 = (const float*)d_in[4];
    const float* W3 = (const float*)d_in[5];
    const float* b3 = (const float*)d_in[6];
    float* out = (float*)d_out;

    const int B = in_sizes[0] / (S_DIM * H_DIM);   // = 2
    const int M = B * S_DIM;                       // 1024

    char* ws = (char*)d_ws;
    _Float16* f16  = (_Float16*)ws;                 // [1024][512] = 1 MB
    _Float16* aH   = (_Float16*)(ws + (1 << 20));   // [1024][512] = 1 MB
    _Float16* cH   = (_Float16*)(ws + (2 << 20));   // [1024][512] = 1 MB
    _Float16* w1L  = (_Float16*)(ws + (3 << 20));   // 1 MB
    _Float16* w2L  = (_Float16*)(ws + (4 << 20));   // 256 KB

    convert_all_kernel<<<832, 256, 0, stream>>>(feats, W1, W2, f16, w1L, w2L);
    prep_mfma_kernel<<<dim3(16, M / 64), 256, 0, stream>>>(f16, w1L, b1, aH, cH);
    pair_kernel<<<dim3(S_DIM / TJ, S_DIM / TI, B), 256, 0, stream>>>(aH, cH, w2L, b2, W3, b3, out);
}